// Round 1
// baseline (775.779 us; speedup 1.0000x reference)
//
#include <hip/hip_runtime.h>

typedef __attribute__((ext_vector_type(8))) short v8s;
typedef __attribute__((ext_vector_type(8))) unsigned short v8u;
typedef __attribute__((ext_vector_type(4))) unsigned short v4u;
typedef __attribute__((ext_vector_type(4))) float f32x4;

#define DEV __device__ __forceinline__

DEV unsigned short f2bf(float f) {
  union { float f; unsigned u; } v; v.f = f;
  unsigned r = v.u + 0x7fffu + ((v.u >> 16) & 1u);
  return (unsigned short)(r >> 16);
}

// ------------------------------------------------------------------
// LayerNorm (torch-style: mean, std ddof=1, (x-mean)/(std+eps)) -> bf16
// one block per row of 1024
// ------------------------------------------------------------------
__global__ __launch_bounds__(256) void ln_kernel(
    const float* __restrict__ x, unsigned short* __restrict__ h,
    const float* __restrict__ alpha, const float* __restrict__ beta)
{
  int row = blockIdx.x;
  int tid = threadIdx.x;
  const float4* xr = reinterpret_cast<const float4*>(x + (size_t)row * 1024);
  float4 v = xr[tid];
  float s  = v.x + v.y + v.z + v.w;
  float ss = v.x * v.x + v.y * v.y + v.z * v.z + v.w * v.w;
#pragma unroll
  for (int off = 1; off < 64; off <<= 1) {
    s  += __shfl_xor(s, off);
    ss += __shfl_xor(ss, off);
  }
  __shared__ float ps[4][2];
  int wid = tid >> 6, lane = tid & 63;
  if (lane == 0) { ps[wid][0] = s; ps[wid][1] = ss; }
  __syncthreads();
  s  = ps[0][0] + ps[1][0] + ps[2][0] + ps[3][0];
  ss = ps[0][1] + ps[1][1] + ps[2][1] + ps[3][1];
  float mean = s * (1.0f / 1024.0f);
  float var  = (ss - 1024.0f * mean * mean) * (1.0f / 1023.0f);
  float inv  = 1.0f / (sqrtf(fmaxf(var, 0.0f)) + 1e-6f);
  float a = alpha[0], b = beta[0];
  v4u o;
  o[0] = f2bf(a * ((v.x - mean) * inv) + b);
  o[1] = f2bf(a * ((v.y - mean) * inv) + b);
  o[2] = f2bf(a * ((v.z - mean) * inv) + b);
  o[3] = f2bf(a * ((v.w - mean) * inv) + b);
  *reinterpret_cast<v4u*>(h + (size_t)row * 1024 + tid * 4) = o;
}

// ------------------------------------------------------------------
// fp32 W[K][N] -> bf16 Wt[N][K]   (32x32 LDS tile transpose)
// block (32,8)
// ------------------------------------------------------------------
__global__ __launch_bounds__(256) void transpose_convert(
    const float* __restrict__ W, unsigned short* __restrict__ Wt, int K, int N)
{
  __shared__ float t[32][33];
  int n0 = blockIdx.x * 32, k0 = blockIdx.y * 32;
  int tx = threadIdx.x, ty = threadIdx.y;
#pragma unroll
  for (int i = 0; i < 4; ++i)
    t[ty + i * 8][tx] = W[(size_t)(k0 + ty + i * 8) * N + n0 + tx];
  __syncthreads();
#pragma unroll
  for (int i = 0; i < 4; ++i)
    Wt[(size_t)(n0 + ty + i * 8) * K + k0 + tx] = f2bf(t[tx][ty + i * 8]);
}

// ------------------------------------------------------------------
// bf16 GEMM: C[M][N] = A[M][K] * Bt[N][K]^T + bias, templated epilogue
// 128x128 tile, BK=32, 4 waves (2x2), each wave 64x64 (4x4 MFMA frags)
// ------------------------------------------------------------------
enum { MODE_QK = 0, MODE_VT = 1, MODE_RES = 2, MODE_FFN1 = 3 };

template <int MODE>
__global__ __launch_bounds__(256) void gemm_bf16(
    const unsigned short* __restrict__ A, const unsigned short* __restrict__ Bt,
    const float* __restrict__ bias, const float* __restrict__ resid,
    void* __restrict__ out, int M, int N, int K)
{
  __shared__ unsigned short As[128][40];
  __shared__ unsigned short Bs[128][40];
  int tid = threadIdx.x, lane = tid & 63, wid = tid >> 6;
  int wr = (wid >> 1) * 64, wc = (wid & 1) * 64;
  int rowBase = blockIdx.x * 128, colBase = blockIdx.y * 128;

  f32x4 acc[4][4];
#pragma unroll
  for (int m = 0; m < 4; ++m)
#pragma unroll
    for (int n = 0; n < 4; ++n) acc[m][n] = (f32x4){0.f, 0.f, 0.f, 0.f};

  for (int k0 = 0; k0 < K; k0 += 32) {
#pragma unroll
    for (int it = 0; it < 2; ++it) {
      int idx = tid + it * 256;
      int r = idx >> 2, c = (idx & 3) * 8;
      *reinterpret_cast<v8u*>(&As[r][c]) =
          *reinterpret_cast<const v8u*>(&A[(size_t)(rowBase + r) * K + k0 + c]);
      *reinterpret_cast<v8u*>(&Bs[r][c]) =
          *reinterpret_cast<const v8u*>(&Bt[(size_t)(colBase + r) * K + k0 + c]);
    }
    __syncthreads();
    v8s af[4], bfr[4];
#pragma unroll
    for (int m = 0; m < 4; ++m)
      af[m] = *reinterpret_cast<const v8s*>(&As[wr + m * 16 + (lane & 15)][(lane >> 4) * 8]);
#pragma unroll
    for (int n = 0; n < 4; ++n)
      bfr[n] = *reinterpret_cast<const v8s*>(&Bs[wc + n * 16 + (lane & 15)][(lane >> 4) * 8]);
#pragma unroll
    for (int m = 0; m < 4; ++m)
#pragma unroll
      for (int n = 0; n < 4; ++n)
        acc[m][n] = __builtin_amdgcn_mfma_f32_16x16x32_bf16(af[m], bfr[n], acc[m][n], 0, 0, 0);
    __syncthreads();
  }

  int g = lane >> 4, c0 = lane & 15;
#pragma unroll
  for (int m = 0; m < 4; ++m) {
#pragma unroll
    for (int n = 0; n < 4; ++n) {
#pragma unroll
      for (int r = 0; r < 4; ++r) {
        int row = rowBase + wr + m * 16 + g * 4 + r;
        int col = colBase + wc + n * 16 + c0;
        float v = acc[m][n][r] + bias[col];
        if constexpr (MODE == MODE_QK) {
          int b = row >> 11, sI = row & 2047, hh = col >> 6, d = col & 63;
          ((unsigned short*)out)[(((size_t)(b * 16 + hh)) * 2048 + sI) * 64 + d] = f2bf(v);
        } else if constexpr (MODE == MODE_VT) {
          int b = row >> 11, sI = row & 2047, hh = col >> 6, d = col & 63;
          ((unsigned short*)out)[(((size_t)(b * 16 + hh)) * 64 + d) * 2048 + sI] = f2bf(v);
        } else if constexpr (MODE == MODE_RES) {
          ((float*)out)[(size_t)row * N + col] = resid[(size_t)row * N + col] + v;
        } else { // MODE_FFN1
          ((unsigned short*)out)[(size_t)row * N + col] = f2bf(fmaxf(v, 0.0f));
        }
      }
    }
  }
}

// ------------------------------------------------------------------
// Flash attention: q,k [bh][S][64] bf16, vT [bh][64][S] bf16 -> ctx [B*S][1024]
// block = 4 waves, 64 q-rows (16/wave); K/V tiles of 32 staged in LDS
// ------------------------------------------------------------------
__global__ __launch_bounds__(256) void attn_kernel(
    const unsigned short* __restrict__ q, const unsigned short* __restrict__ k,
    const unsigned short* __restrict__ vT, const int* __restrict__ mask,
    unsigned short* __restrict__ ctx)
{
  const int S = 2048, DK = 64;
  int bh = blockIdx.x;           // 0..63
  int b = bh >> 4, hh = bh & 15;
  int qbase = blockIdx.y * 64;
  int tid = threadIdx.x, lane = tid & 63, wid = tid >> 6;
  int g = lane >> 4, c0 = lane & 15;

  __shared__ unsigned short Ks[32][72];
  __shared__ unsigned short Vs[64][40];
  __shared__ unsigned short Ps[4][16][40];

  const unsigned short* qb = q  + (size_t)bh * S * DK;
  const unsigned short* kb = k  + (size_t)bh * S * DK;
  const unsigned short* vb = vT + (size_t)bh * DK * S;

  // Q fragments for this wave's 16 rows (A operand, 2 K-steps of 32)
  v8s aq[2];
  int qrow = qbase + wid * 16 + c0;
#pragma unroll
  for (int t = 0; t < 2; ++t)
    aq[t] = *reinterpret_cast<const v8s*>(&qb[(size_t)qrow * DK + t * 32 + g * 8]);

  f32x4 acc_o[4];
#pragma unroll
  for (int no = 0; no < 4; ++no) acc_o[no] = (f32x4){0.f, 0.f, 0.f, 0.f};
  float mrow[4] = {-1e30f, -1e30f, -1e30f, -1e30f};
  float lrow[4] = {0.f, 0.f, 0.f, 0.f};

  for (int kt = 0; kt < S; kt += 32) {
    // stage K tile 32x64 and V^T tile 64x32
    *reinterpret_cast<v8u*>(&Ks[tid >> 3][(tid & 7) * 8]) =
        *reinterpret_cast<const v8u*>(&kb[(size_t)(kt + (tid >> 3)) * DK + (tid & 7) * 8]);
    *reinterpret_cast<v8u*>(&Vs[tid >> 2][(tid & 3) * 8]) =
        *reinterpret_cast<const v8u*>(&vb[(size_t)(tid >> 2) * S + kt + (tid & 3) * 8]);
    __syncthreads();

    f32x4 sa[2];
    sa[0] = (f32x4){0.f, 0.f, 0.f, 0.f};
    sa[1] = (f32x4){0.f, 0.f, 0.f, 0.f};
#pragma unroll
    for (int n = 0; n < 2; ++n)
#pragma unroll
      for (int t = 0; t < 2; ++t) {
        v8s bk = *reinterpret_cast<const v8s*>(&Ks[n * 16 + c0][t * 32 + g * 8]);
        sa[n] = __builtin_amdgcn_mfma_f32_16x16x32_bf16(aq[t], bk, sa[n], 0, 0, 0);
      }

    // online softmax for rows 4g..4g+3 (replicated across the 16-lane group)
    int ok0 = mask[b * S + kt + c0];
    int ok1 = mask[b * S + kt + 16 + c0];
    float pv0[4], pv1[4], scl[4];
#pragma unroll
    for (int r = 0; r < 4; ++r) {
      float s0 = ok0 ? sa[0][r] * 0.125f : -1e9f;
      float s1 = ok1 ? sa[1][r] * 0.125f : -1e9f;
      float tm = fmaxf(s0, s1);
#pragma unroll
      for (int off = 1; off < 16; off <<= 1) tm = fmaxf(tm, __shfl_xor(tm, off));
      float mn = fmaxf(mrow[r], tm);
      float sc = __expf(mrow[r] - mn);
      float p0 = __expf(s0 - mn), p1 = __expf(s1 - mn);
      float ts = p0 + p1;
#pragma unroll
      for (int off = 1; off < 16; off <<= 1) ts += __shfl_xor(ts, off);
      lrow[r] = lrow[r] * sc + ts;
      mrow[r] = mn;
      scl[r] = sc;
      pv0[r] = p0; pv1[r] = p1;
    }
#pragma unroll
    for (int no = 0; no < 4; ++no)
#pragma unroll
      for (int r = 0; r < 4; ++r) acc_o[no][r] *= scl[r];

    // write P (bf16) to per-wave LDS, transposed read as A operand
#pragma unroll
    for (int r = 0; r < 4; ++r) {
      Ps[wid][g * 4 + r][c0]      = f2bf(pv0[r]);
      Ps[wid][g * 4 + r][16 + c0] = f2bf(pv1[r]);
    }
    __syncthreads();

    v8s ap = *reinterpret_cast<const v8s*>(&Ps[wid][c0][g * 8]);
#pragma unroll
    for (int no = 0; no < 4; ++no) {
      v8s bv = *reinterpret_cast<const v8s*>(&Vs[no * 16 + c0][g * 8]);
      acc_o[no] = __builtin_amdgcn_mfma_f32_16x16x32_bf16(ap, bv, acc_o[no], 0, 0, 0);
    }
    __syncthreads();
  }

  // epilogue: normalize and write ctx rows
#pragma unroll
  for (int no = 0; no < 4; ++no)
#pragma unroll
    for (int r = 0; r < 4; ++r) {
      float o = acc_o[no][r] / fmaxf(lrow[r], 1e-20f);
      int srow = qbase + wid * 16 + g * 4 + r;
      int d = no * 16 + c0;
      ctx[(size_t)(b * S + srow) * 1024 + hh * 64 + d] = f2bf(o);
    }
}

// ------------------------------------------------------------------
extern "C" void kernel_launch(void* const* d_in, const int* in_sizes, int n_in,
                              void* d_out, int out_size, void* d_ws, size_t ws_size,
                              hipStream_t stream)
{
  (void)in_sizes; (void)n_in; (void)out_size; (void)ws_size;
  const float* x    = (const float*)d_in[0];
  const int*   mask = (const int*)d_in[1];
  const float* Wq = (const float*)d_in[2];  const float* bq = (const float*)d_in[3];
  const float* Wk = (const float*)d_in[4];  const float* bk = (const float*)d_in[5];
  const float* Wv = (const float*)d_in[6];  const float* bv = (const float*)d_in[7];
  const float* Wo = (const float*)d_in[8];  const float* bo = (const float*)d_in[9];
  const float* W1 = (const float*)d_in[10]; const float* b1 = (const float*)d_in[11];
  const float* W2 = (const float*)d_in[12]; const float* b2 = (const float*)d_in[13];
  const float* ln1a = (const float*)d_in[14]; const float* ln1b = (const float*)d_in[15];
  const float* ln2a = (const float*)d_in[16]; const float* ln2b = (const float*)d_in[17];

  char* ws = (char*)d_ws;
  const size_t MB = (size_t)1 << 20;
  unsigned short* wqT = (unsigned short*)(ws + 0 * MB);
  unsigned short* wkT = (unsigned short*)(ws + 2 * MB);
  unsigned short* wvT = (unsigned short*)(ws + 4 * MB);
  unsigned short* woT = (unsigned short*)(ws + 6 * MB);
  unsigned short* w1T = (unsigned short*)(ws + 8 * MB);   // [4096][1024]
  unsigned short* w2T = (unsigned short*)(ws + 16 * MB);  // [1024][4096]
  unsigned short* hb  = (unsigned short*)(ws + 24 * MB);  // LN out, 8192x1024
  unsigned short* qb  = (unsigned short*)(ws + 40 * MB);  // [bh][S][64]
  unsigned short* kb  = (unsigned short*)(ws + 56 * MB);
  unsigned short* vTb = (unsigned short*)(ws + 72 * MB);  // [bh][64][S]
  unsigned short* ctx = (unsigned short*)(ws + 88 * MB);  // 8192x1024
  unsigned short* gb  = (unsigned short*)(ws + 40 * MB);  // FFN mid (aliases q/k, dead)
  float* xout = (float*)d_out;                            // x1 lives in d_out

  dim3 tb(32, 8);
  transpose_convert<<<dim3(32, 32),  tb, 0, stream>>>(Wq, wqT, 1024, 1024);
  transpose_convert<<<dim3(32, 32),  tb, 0, stream>>>(Wk, wkT, 1024, 1024);
  transpose_convert<<<dim3(32, 32),  tb, 0, stream>>>(Wv, wvT, 1024, 1024);
  transpose_convert<<<dim3(32, 32),  tb, 0, stream>>>(Wo, woT, 1024, 1024);
  transpose_convert<<<dim3(128, 32), tb, 0, stream>>>(W1, w1T, 1024, 4096);
  transpose_convert<<<dim3(32, 128), tb, 0, stream>>>(W2, w2T, 4096, 1024);

  ln_kernel<<<8192, 256, 0, stream>>>(x, hb, ln1a, ln1b);

  gemm_bf16<MODE_QK><<<dim3(64, 8), 256, 0, stream>>>(hb, wqT, bq, nullptr, qb,  8192, 1024, 1024);
  gemm_bf16<MODE_QK><<<dim3(64, 8), 256, 0, stream>>>(hb, wkT, bk, nullptr, kb,  8192, 1024, 1024);
  gemm_bf16<MODE_VT><<<dim3(64, 8), 256, 0, stream>>>(hb, wvT, bv, nullptr, vTb, 8192, 1024, 1024);

  attn_kernel<<<dim3(64, 32), 256, 0, stream>>>(qb, kb, vTb, mask, ctx);

  gemm_bf16<MODE_RES><<<dim3(64, 8), 256, 0, stream>>>(ctx, woT, bo, x, xout, 8192, 1024, 1024);

  ln_kernel<<<8192, 256, 0, stream>>>(xout, hb, ln2a, ln2b);

  for (int c = 0; c < 2; ++c) {
    const unsigned short* h2c = hb + (size_t)c * 4096 * 1024;
    float* oc = xout + (size_t)c * 4096 * 1024;
    gemm_bf16<MODE_FFN1><<<dim3(32, 32), 256, 0, stream>>>(h2c, w1T, b1, nullptr, gb, 4096, 4096, 1024);
    gemm_bf16<MODE_RES><<<dim3(32, 8),  256, 0, stream>>>(gb, w2T, b2, oc, oc, 4096, 1024, 4096);
  }
}

// Round 2
// 517.531 us; speedup vs baseline: 1.4990x; 1.4990x over previous
//
#include <hip/hip_runtime.h>

typedef __attribute__((ext_vector_type(8))) short v8s;
typedef __attribute__((ext_vector_type(4))) short v4s;
typedef __attribute__((ext_vector_type(8))) unsigned short v8u;
typedef __attribute__((ext_vector_type(4))) unsigned short v4u;
typedef __attribute__((ext_vector_type(4))) float f32x4;

#define DEV __device__ __forceinline__

DEV unsigned short f2bf(float f) {
  union { float f; unsigned u; } v; v.f = f;
  unsigned r = v.u + 0x7fffu + ((v.u >> 16) & 1u);
  return (unsigned short)(r >> 16);
}

DEV void gload16(const unsigned short* g, unsigned short* l) {
  __builtin_amdgcn_global_load_lds(
      (const __attribute__((address_space(1))) unsigned int*)g,
      (__attribute__((address_space(3))) unsigned int*)l, 16, 0, 0);
}

// ------------------------------------------------------------------
// LayerNorm (torch-style: mean, std ddof=1, (x-mean)/(std+eps)) -> bf16
// ------------------------------------------------------------------
__global__ __launch_bounds__(256) void ln_kernel(
    const float* __restrict__ x, unsigned short* __restrict__ h,
    const float* __restrict__ alpha, const float* __restrict__ beta)
{
  int row = blockIdx.x;
  int tid = threadIdx.x;
  const float4* xr = reinterpret_cast<const float4*>(x + (size_t)row * 1024);
  float4 v = xr[tid];
  float s  = v.x + v.y + v.z + v.w;
  float ss = v.x * v.x + v.y * v.y + v.z * v.z + v.w * v.w;
#pragma unroll
  for (int off = 1; off < 64; off <<= 1) {
    s  += __shfl_xor(s, off);
    ss += __shfl_xor(ss, off);
  }
  __shared__ float ps[4][2];
  int wid = tid >> 6, lane = tid & 63;
  if (lane == 0) { ps[wid][0] = s; ps[wid][1] = ss; }
  __syncthreads();
  s  = ps[0][0] + ps[1][0] + ps[2][0] + ps[3][0];
  ss = ps[0][1] + ps[1][1] + ps[2][1] + ps[3][1];
  float mean = s * (1.0f / 1024.0f);
  float var  = (ss - 1024.0f * mean * mean) * (1.0f / 1023.0f);
  float inv  = 1.0f / (sqrtf(fmaxf(var, 0.0f)) + 1e-6f);
  float a = alpha[0], b = beta[0];
  v4u o;
  o[0] = f2bf(a * ((v.x - mean) * inv) + b);
  o[1] = f2bf(a * ((v.y - mean) * inv) + b);
  o[2] = f2bf(a * ((v.z - mean) * inv) + b);
  o[3] = f2bf(a * ((v.w - mean) * inv) + b);
  *reinterpret_cast<v4u*>(h + (size_t)row * 1024 + tid * 4) = o;
}

// ------------------------------------------------------------------
// fp32 W[K][N] -> bf16 Wt[N][K]
// ------------------------------------------------------------------
__global__ __launch_bounds__(256) void transpose_convert(
    const float* __restrict__ W, unsigned short* __restrict__ Wt, int K, int N)
{
  __shared__ float t[32][33];
  int n0 = blockIdx.x * 32, k0 = blockIdx.y * 32;
  int tx = threadIdx.x, ty = threadIdx.y;
#pragma unroll
  for (int i = 0; i < 4; ++i)
    t[ty + i * 8][tx] = W[(size_t)(k0 + ty + i * 8) * N + n0 + tx];
  __syncthreads();
#pragma unroll
  for (int i = 0; i < 4; ++i)
    Wt[(size_t)(n0 + ty + i * 8) * K + k0 + tx] = f2bf(t[tx][ty + i * 8]);
}

// ------------------------------------------------------------------
// bf16 GEMM (m97 structure): 128x128 tile, BK=32, linear LDS,
// global_load_lds width-16 staging, 4 waves (2x2), 4x4 MFMA frags/wave
// ------------------------------------------------------------------
enum { MODE_QK = 0, MODE_VT = 1, MODE_RES = 2, MODE_FFN1 = 3 };

template <int MODE>
__global__ __launch_bounds__(256) void gemm_bf16(
    const unsigned short* __restrict__ A, const unsigned short* __restrict__ Bt,
    const float* __restrict__ bias, const float* __restrict__ resid,
    void* __restrict__ out, int M, int N, int K)
{
  __shared__ unsigned short As[128][32];
  __shared__ unsigned short Bs[128][32];
  int tid = threadIdx.x, lane = tid & 63, wid = tid >> 6;
  int wr = (wid >> 1) * 64, wc = (wid & 1) * 64;
  int rowBase = blockIdx.x * 128, colBase = blockIdx.y * 128;

  f32x4 acc[4][4];
#pragma unroll
  for (int m = 0; m < 4; ++m)
#pragma unroll
    for (int n = 0; n < 4; ++n) acc[m][n] = (f32x4){0.f, 0.f, 0.f, 0.f};

  int srow = lane >> 2;            // 0..15 within a 16-row slab
  int scol = (lane & 3) * 8;       // element column
  const unsigned short* gA = A + (size_t)rowBase * K + scol;
  const unsigned short* gB = Bt + (size_t)colBase * K + scol;
  unsigned short* lA = &As[0][0];
  unsigned short* lB = &Bs[0][0];

  for (int k0 = 0; k0 < K; k0 += 32) {
#pragma unroll
    for (int i = 0; i < 2; ++i) {
      int rblk = (i * 4 + wid) * 16;   // wave-uniform starting row
      gload16(gA + (size_t)(rblk + srow) * K + k0, lA + rblk * 32);
      gload16(gB + (size_t)(rblk + srow) * K + k0, lB + rblk * 32);
    }
    __syncthreads();
    v8s af[4], bfr[4];
#pragma unroll
    for (int m = 0; m < 4; ++m)
      af[m] = *reinterpret_cast<const v8s*>(&As[wr + m * 16 + (lane & 15)][(lane >> 4) * 8]);
#pragma unroll
    for (int n = 0; n < 4; ++n)
      bfr[n] = *reinterpret_cast<const v8s*>(&Bs[wc + n * 16 + (lane & 15)][(lane >> 4) * 8]);
#pragma unroll
    for (int m = 0; m < 4; ++m)
#pragma unroll
      for (int n = 0; n < 4; ++n)
        acc[m][n] = __builtin_amdgcn_mfma_f32_16x16x32_bf16(af[m], bfr[n], acc[m][n], 0, 0, 0);
    __syncthreads();
  }

  int g = lane >> 4, c0 = lane & 15;
#pragma unroll
  for (int m = 0; m < 4; ++m) {
#pragma unroll
    for (int n = 0; n < 4; ++n) {
#pragma unroll
      for (int r = 0; r < 4; ++r) {
        int row = rowBase + wr + m * 16 + g * 4 + r;
        int col = colBase + wc + n * 16 + c0;
        float v = acc[m][n][r] + bias[col];
        if constexpr (MODE == MODE_QK) {
          int b = row >> 11, sI = row & 2047, hh = col >> 6, d = col & 63;
          ((unsigned short*)out)[(((size_t)(b * 16 + hh)) * 2048 + sI) * 64 + d] = f2bf(v);
        } else if constexpr (MODE == MODE_VT) {
          int b = row >> 11, sI = row & 2047, hh = col >> 6, d = col & 63;
          ((unsigned short*)out)[(((size_t)(b * 16 + hh)) * 64 + d) * 2048 + sI] = f2bf(v);
        } else if constexpr (MODE == MODE_RES) {
          ((float*)out)[(size_t)row * N + col] = resid[(size_t)row * N + col] + v;
        } else { // MODE_FFN1
          ((unsigned short*)out)[(size_t)row * N + col] = f2bf(fmaxf(v, 0.0f));
        }
      }
    }
  }
}

// ------------------------------------------------------------------
// Flash attention, swapped-operand form.
// Per wave: 16 q-rows; lane owns q = lane&15 (softmax state per-lane).
// S^T = mfma(K, Q); O^T = mfma(V^T, P^T) with shared k-permutation.
// K/V LDS tiles XOR-swizzled at 16B granularity (row&7)<<4.
// ------------------------------------------------------------------
__global__ __launch_bounds__(256) void attn_kernel(
    const unsigned short* __restrict__ q, const unsigned short* __restrict__ k,
    const unsigned short* __restrict__ vT, const int* __restrict__ mask,
    unsigned short* __restrict__ ctx)
{
  const int S = 2048, DK = 64, KVB = 64;
  int bh = blockIdx.x;             // 0..63
  int b = bh >> 4, hh = bh & 15;
  int qbase = blockIdx.y * 64;
  int tid = threadIdx.x, lane = tid & 63, wid = tid >> 6;
  int g = lane >> 4, c0 = lane & 15;

  __shared__ unsigned short Ks[KVB][DK];   // [kv][dk], swizzled
  __shared__ unsigned short Vs[DK][KVB];   // [d][kv],  swizzled
  __shared__ float Msf[KVB];

  const unsigned short* qb = q  + (size_t)bh * S * DK;
  const unsigned short* kb = k  + (size_t)bh * S * DK;
  const unsigned short* vb = vT + (size_t)bh * DK * S;

  // Q fragment (B-operand): col = q = lane&15, slots dk = t*32 + g*8 + j
  int qrow = qbase + wid * 16 + c0;
  v8s aq[2];
#pragma unroll
  for (int t = 0; t < 2; ++t)
    aq[t] = *reinterpret_cast<const v8s*>(&qb[(size_t)qrow * DK + t * 32 + g * 8]);

  f32x4 acc[4];                    // O^T: d = no*16 + g*4 + r, q = c0
#pragma unroll
  for (int no = 0; no < 4; ++no) acc[no] = (f32x4){0.f, 0.f, 0.f, 0.f};
  float mrow = -1e30f, lrow = 0.f;

  for (int kt = 0; kt < S; kt += KVB) {
    // ---- stage K (64x64) and V^T (64x64), swizzled ----
#pragma unroll
    for (int p = 0; p < 2; ++p) {
      int idx = tid + p * 256;                 // 0..511
      int r = idx >> 3;                        // kv row / d row
      int cb = (idx & 7) * 16;                 // byte col
      int sw = cb ^ ((r & 7) << 4);
      *reinterpret_cast<v8u*>((char*)&Ks[r][0] + sw) =
          *reinterpret_cast<const v8u*>((const char*)&kb[(size_t)(kt + r) * DK] + cb);
      *reinterpret_cast<v8u*>((char*)&Vs[r][0] + sw) =
          *reinterpret_cast<const v8u*>((const char*)&vb[(size_t)r * S + kt] + cb);
    }
    if (tid < KVB) Msf[tid] = mask[b * S + kt + tid] ? 0.f : -1e9f;
    __syncthreads();

    // ---- S^T = K * Q^T : p[n*4+r] = S[k = n*16+g*4+r][q = c0] ----
    float p[16];
#pragma unroll
    for (int n = 0; n < 4; ++n) {
      f32x4 sa = (f32x4){0.f, 0.f, 0.f, 0.f};
#pragma unroll
      for (int t = 0; t < 2; ++t) {
        int kvr = n * 16 + c0;
        int cb = (t * 32 + g * 8) * 2;
        int sw = cb ^ ((kvr & 7) << 4);
        v8s ak = *reinterpret_cast<const v8s*>((const char*)&Ks[kvr][0] + sw);
        sa = __builtin_amdgcn_mfma_f32_16x16x32_bf16(ak, aq[t], sa, 0, 0, 0);
      }
      f32x4 bn = *reinterpret_cast<const f32x4*>(&Msf[n * 16 + g * 4]);
#pragma unroll
      for (int r = 0; r < 4; ++r) p[n * 4 + r] = sa[r] * 0.125f + bn[r];
    }

    // ---- online softmax: per-lane register reduce + 2 shfl ----
    float tm = p[0];
#pragma unroll
    for (int i = 1; i < 16; ++i) tm = fmaxf(tm, p[i]);
    tm = fmaxf(tm, __shfl_xor(tm, 16));
    tm = fmaxf(tm, __shfl_xor(tm, 32));
    float mn = fmaxf(mrow, tm);
    float sc = __expf(mrow - mn);
    float ts = 0.f;
#pragma unroll
    for (int i = 0; i < 16; ++i) { p[i] = __expf(p[i] - mn); ts += p[i]; }
    ts += __shfl_xor(ts, 16);
    ts += __shfl_xor(ts, 32);
    lrow = lrow * sc + ts;
    mrow = mn;
#pragma unroll
    for (int no = 0; no < 4; ++no) {
      acc[no][0] *= sc; acc[no][1] *= sc; acc[no][2] *= sc; acc[no][3] *= sc;
    }

    // ---- O^T += V^T * P^T (shared k-permutation pi(g,j)=16(j>>2)+4g+(j&3)) ----
#pragma unroll
    for (int c = 0; c < 2; ++c) {
      v8s pbv;
#pragma unroll
      for (int j = 0; j < 8; ++j) pbv[j] = (short)f2bf(p[c * 8 + j]);
#pragma unroll
      for (int no = 0; no < 4; ++no) {
        int d = no * 16 + c0;
        int sw = (d & 7) << 4;
        const char* vrow = (const char*)&Vs[d][0];
        v4s lo = *reinterpret_cast<const v4s*>(vrow + (((c * 64) + g * 8) ^ sw));
        v4s hi = *reinterpret_cast<const v4s*>(vrow + (((c * 64 + 32) + g * 8) ^ sw));
        v8s av = {lo[0], lo[1], lo[2], lo[3], hi[0], hi[1], hi[2], hi[3]};
        acc[no] = __builtin_amdgcn_mfma_f32_16x16x32_bf16(av, pbv, acc[no], 0, 0, 0);
      }
    }
    __syncthreads();
  }

  // ---- epilogue: O[q][d] = acc / lrow ----
  float inv = 1.0f / fmaxf(lrow, 1e-20f);
#pragma unroll
  for (int no = 0; no < 4; ++no) {
    v4u o;
    o[0] = f2bf(acc[no][0] * inv);
    o[1] = f2bf(acc[no][1] * inv);
    o[2] = f2bf(acc[no][2] * inv);
    o[3] = f2bf(acc[no][3] * inv);
    *reinterpret_cast<v4u*>(
        &ctx[(size_t)(b * S + qrow) * 1024 + hh * 64 + no * 16 + g * 4]) = o;
  }
}

// ------------------------------------------------------------------
extern "C" void kernel_launch(void* const* d_in, const int* in_sizes, int n_in,
                              void* d_out, int out_size, void* d_ws, size_t ws_size,
                              hipStream_t stream)
{
  (void)in_sizes; (void)n_in; (void)out_size; (void)ws_size;
  const float* x    = (const float*)d_in[0];
  const int*   mask = (const int*)d_in[1];
  const float* Wq = (const float*)d_in[2];  const float* bq = (const float*)d_in[3];
  const float* Wk = (const float*)d_in[4];  const float* bk = (const float*)d_in[5];
  const float* Wv = (const float*)d_in[6];  const float* bv = (const float*)d_in[7];
  const float* Wo = (const float*)d_in[8];  const float* bo = (const float*)d_in[9];
  const float* W1 = (const float*)d_in[10]; const float* b1 = (const float*)d_in[11];
  const float* W2 = (const float*)d_in[12]; const float* b2 = (const float*)d_in[13];
  const float* ln1a = (const float*)d_in[14]; const float* ln1b = (const float*)d_in[15];
  const float* ln2a = (const float*)d_in[16]; const float* ln2b = (const float*)d_in[17];

  char* ws = (char*)d_ws;
  const size_t MB = (size_t)1 << 20;
  unsigned short* wqT = (unsigned short*)(ws + 0 * MB);
  unsigned short* wkT = (unsigned short*)(ws + 2 * MB);
  unsigned short* wvT = (unsigned short*)(ws + 4 * MB);
  unsigned short* woT = (unsigned short*)(ws + 6 * MB);
  unsigned short* w1T = (unsigned short*)(ws + 8 * MB);   // [4096][1024]
  unsigned short* w2T = (unsigned short*)(ws + 16 * MB);  // [1024][4096]
  unsigned short* hb  = (unsigned short*)(ws + 24 * MB);  // LN out, 8192x1024
  unsigned short* qb  = (unsigned short*)(ws + 40 * MB);  // [bh][S][64]
  unsigned short* kb  = (unsigned short*)(ws + 56 * MB);
  unsigned short* vTb = (unsigned short*)(ws + 72 * MB);  // [bh][64][S]
  unsigned short* ctx = (unsigned short*)(ws + 88 * MB);  // 8192x1024
  unsigned short* gb  = (unsigned short*)(ws + 40 * MB);  // FFN mid 8192x4096 (40..104, aliases q/k/v/ctx, all dead)
  float* xout = (float*)d_out;

  dim3 tb(32, 8);
  transpose_convert<<<dim3(32, 32),  tb, 0, stream>>>(Wq, wqT, 1024, 1024);
  transpose_convert<<<dim3(32, 32),  tb, 0, stream>>>(Wk, wkT, 1024, 1024);
  transpose_convert<<<dim3(32, 32),  tb, 0, stream>>>(Wv, wvT, 1024, 1024);
  transpose_convert<<<dim3(32, 32),  tb, 0, stream>>>(Wo, woT, 1024, 1024);
  transpose_convert<<<dim3(128, 32), tb, 0, stream>>>(W1, w1T, 1024, 4096);
  transpose_convert<<<dim3(32, 128), tb, 0, stream>>>(W2, w2T, 4096, 1024);

  ln_kernel<<<8192, 256, 0, stream>>>(x, hb, ln1a, ln1b);

  gemm_bf16<MODE_QK><<<dim3(64, 8), 256, 0, stream>>>(hb, wqT, bq, nullptr, qb,  8192, 1024, 1024);
  gemm_bf16<MODE_QK><<<dim3(64, 8), 256, 0, stream>>>(hb, wkT, bk, nullptr, kb,  8192, 1024, 1024);
  gemm_bf16<MODE_VT><<<dim3(64, 8), 256, 0, stream>>>(hb, wvT, bv, nullptr, vTb, 8192, 1024, 1024);

  attn_kernel<<<dim3(64, 32), 256, 0, stream>>>(qb, kb, vTb, mask, ctx);

  gemm_bf16<MODE_RES><<<dim3(64, 8), 256, 0, stream>>>(ctx, woT, bo, x, xout, 8192, 1024, 1024);

  ln_kernel<<<8192, 256, 0, stream>>>(xout, hb, ln2a, ln2b);

  gemm_bf16<MODE_FFN1><<<dim3(64, 32), 256, 0, stream>>>(hb, w1T, b1, nullptr, gb, 8192, 4096, 1024);
  gemm_bf16<MODE_RES><<<dim3(64, 8),  256, 0, stream>>>(gb, w2T, b2, xout, xout, 8192, 1024, 4096);
}

// Round 4
// 485.045 us; speedup vs baseline: 1.5994x; 1.0670x over previous
//
#include <hip/hip_runtime.h>

typedef __attribute__((ext_vector_type(8))) short v8s;
typedef __attribute__((ext_vector_type(4))) short v4s;
typedef __attribute__((ext_vector_type(8))) unsigned short v8u;
typedef __attribute__((ext_vector_type(4))) unsigned short v4u;
typedef __attribute__((ext_vector_type(4))) float f32x4;

#define DEV __device__ __forceinline__

DEV unsigned short f2bf(float f) {
  union { float f; unsigned u; } v; v.f = f;
  unsigned r = v.u + 0x7fffu + ((v.u >> 16) & 1u);
  return (unsigned short)(r >> 16);
}

DEV void gload16(const unsigned short* g, unsigned short* l) {
  __builtin_amdgcn_global_load_lds(
      (const __attribute__((address_space(1))) unsigned int*)g,
      (__attribute__((address_space(3))) unsigned int*)l, 16, 0, 0);
}

// ------------------------------------------------------------------
// LayerNorm (torch-style: mean, std ddof=1, (x-mean)/(std+eps)) -> bf16
// ------------------------------------------------------------------
__global__ __launch_bounds__(256) void ln_kernel(
    const float* __restrict__ x, unsigned short* __restrict__ h,
    const float* __restrict__ alpha, const float* __restrict__ beta)
{
  int row = blockIdx.x;
  int tid = threadIdx.x;
  const float4* xr = reinterpret_cast<const float4*>(x + (size_t)row * 1024);
  float4 v = xr[tid];
  float s  = v.x + v.y + v.z + v.w;
  float ss = v.x * v.x + v.y * v.y + v.z * v.z + v.w * v.w;
#pragma unroll
  for (int off = 1; off < 64; off <<= 1) {
    s  += __shfl_xor(s, off);
    ss += __shfl_xor(ss, off);
  }
  __shared__ float ps[4][2];
  int wid = tid >> 6, lane = tid & 63;
  if (lane == 0) { ps[wid][0] = s; ps[wid][1] = ss; }
  __syncthreads();
  s  = ps[0][0] + ps[1][0] + ps[2][0] + ps[3][0];
  ss = ps[0][1] + ps[1][1] + ps[2][1] + ps[3][1];
  float mean = s * (1.0f / 1024.0f);
  float var  = (ss - 1024.0f * mean * mean) * (1.0f / 1023.0f);
  float inv  = 1.0f / (sqrtf(fmaxf(var, 0.0f)) + 1e-6f);
  float a = alpha[0], b = beta[0];
  v4u o;
  o[0] = f2bf(a * ((v.x - mean) * inv) + b);
  o[1] = f2bf(a * ((v.y - mean) * inv) + b);
  o[2] = f2bf(a * ((v.z - mean) * inv) + b);
  o[3] = f2bf(a * ((v.w - mean) * inv) + b);
  *reinterpret_cast<v4u*>(h + (size_t)row * 1024 + tid * 4) = o;
}

// ------------------------------------------------------------------
// fp32 W[K][N] -> bf16 Wt[N][K]
// ------------------------------------------------------------------
__global__ __launch_bounds__(256) void transpose_convert(
    const float* __restrict__ W, unsigned short* __restrict__ Wt, int K, int N)
{
  __shared__ float t[32][33];
  int n0 = blockIdx.x * 32, k0 = blockIdx.y * 32;
  int tx = threadIdx.x, ty = threadIdx.y;
#pragma unroll
  for (int i = 0; i < 4; ++i)
    t[ty + i * 8][tx] = W[(size_t)(k0 + ty + i * 8) * N + n0 + tx];
  __syncthreads();
#pragma unroll
  for (int i = 0; i < 4; ++i)
    Wt[(size_t)(n0 + ty + i * 8) * K + k0 + tx] = f2bf(t[tx][ty + i * 8]);
}

// ------------------------------------------------------------------
// Pipelined bf16 GEMM: tile 128x256, BK=64, 8 waves (2M x 4N),
// 3 LDS K-tile buffers (race-free deep prefetch), counted vmcnt(6),
// raw s_barrier (no vmcnt drain), XOR-swizzled LDS via pre-swizzled
// global_load_lds source, setprio around MFMA, bijective XCD swizzle.
// ------------------------------------------------------------------
enum { MODE_QK = 0, MODE_VT = 1, MODE_RES = 2, MODE_FFN1 = 3 };

#define BUF_ELEMS ((128 + 256) * 64)

DEV void stage_part(const unsigned short* Aptr, const unsigned short* Bptr,
                    unsigned short* buf, int K, int part, int wid, int lane)
{
  // part 0: A slab 0, B slabs 0,1 ; part 1: A slab 1, B slabs 2,3
  {
    int d = (part * 8 + wid) * 64 + lane;      // A granule 0..1023
    int r = d >> 3, p = d & 7;
    gload16(Aptr + (size_t)r * K + 8 * (p ^ (r & 7)),
            buf + (size_t)(part * 8 + wid) * 512);
  }
#pragma unroll
  for (int j = 0; j < 2; ++j) {
    int ib = part * 2 + j;
    int d = (ib * 8 + wid) * 64 + lane;        // B granule 0..2047
    int r = d >> 3, p = d & 7;
    gload16(Bptr + (size_t)r * K + 8 * (p ^ (r & 7)),
            buf + 128 * 64 + (size_t)(ib * 8 + wid) * 512);
  }
}

template <int MODE>
__global__ __launch_bounds__(512, 2) void gemm_pipe(
    const unsigned short* __restrict__ A, const unsigned short* __restrict__ Bt,
    const float* __restrict__ bias, const float* __restrict__ resid,
    void* __restrict__ out, int M, int N, int K)
{
  __shared__ unsigned short lds[3 * BUF_ELEMS];

  int nbx = M >> 7, nwg = gridDim.x;
  int lin = blockIdx.x;
  int qq = nwg >> 3, rr = nwg & 7;
  int xcd = lin & 7, idx = lin >> 3;
  int swz = (xcd < rr ? xcd * (qq + 1) : rr * (qq + 1) + (xcd - rr) * qq) + idx;
  int bx = swz % nbx, by = swz / nbx;

  int tid = threadIdx.x, lane = tid & 63, wid = tid >> 6;
  int wm = wid >> 2, wn = wid & 3;
  int g = lane >> 4, c0 = lane & 15;
  int rowBase = bx * 128, colBase = by * 256;

  const unsigned short* Ab = A  + (size_t)rowBase * K;
  const unsigned short* Bb = Bt + (size_t)colBase * K;
  int NT = K >> 6;

  f32x4 acc[4][4];
#pragma unroll
  for (int m = 0; m < 4; ++m)
#pragma unroll
    for (int n = 0; n < 4; ++n) acc[m][n] = (f32x4){0.f, 0.f, 0.f, 0.f};

  // prologue: stage tiles 0 and 1
  stage_part(Ab, Bb, lds, K, 0, wid, lane);
  stage_part(Ab, Bb, lds, K, 1, wid, lane);
  stage_part(Ab + 64, Bb + 64, lds + BUF_ELEMS, K, 0, wid, lane);
  stage_part(Ab + 64, Bb + 64, lds + BUF_ELEMS, K, 1, wid, lane);
  asm volatile("s_waitcnt vmcnt(6)" ::: "memory");
  __builtin_amdgcn_s_barrier();
  asm volatile("" ::: "memory");

  int cur = 0;
  for (int t = 0; t < NT; ++t) {
    const char* Abuf = (const char*)(lds + cur * BUF_ELEMS);
    const char* Bbuf = Abuf + 128 * 128;
    int nxt2 = cur + 2; if (nxt2 >= 3) nxt2 -= 3;
    unsigned short* sbuf = lds + nxt2 * BUF_ELEMS;
    bool doStage = (t + 2 < NT);
    int ks = (t + 2) << 6;
    int e = (c0 & 7) << 4;

#pragma unroll
    for (int ph = 0; ph < 2; ++ph) {
      v8s af[2][2], bfr[4][2];
#pragma unroll
      for (int mq = 0; mq < 2; ++mq)
#pragma unroll
        for (int kk = 0; kk < 2; ++kk)
          af[mq][kk] = *reinterpret_cast<const v8s*>(
              Abuf + (wm * 64 + (ph * 2 + mq) * 16 + c0) * 128 + ((kk * 64 + g * 16) ^ e));
#pragma unroll
      for (int n = 0; n < 4; ++n)
#pragma unroll
        for (int kk = 0; kk < 2; ++kk)
          bfr[n][kk] = *reinterpret_cast<const v8s*>(
              Bbuf + (wn * 64 + n * 16 + c0) * 128 + ((kk * 64 + g * 16) ^ e));

      if (doStage) stage_part(Ab + ks, Bb + ks, sbuf, K, ph, wid, lane);

      __builtin_amdgcn_s_setprio(1);
#pragma unroll
      for (int kk = 0; kk < 2; ++kk)
#pragma unroll
        for (int mq = 0; mq < 2; ++mq)
#pragma unroll
          for (int n = 0; n < 4; ++n)
            acc[ph * 2 + mq][n] = __builtin_amdgcn_mfma_f32_16x16x32_bf16(
                af[mq][kk], bfr[n][kk], acc[ph * 2 + mq][n], 0, 0, 0);
      __builtin_amdgcn_s_setprio(0);

      if (ph == 1) {
        if (doStage) asm volatile("s_waitcnt vmcnt(6)" ::: "memory");
        else         asm volatile("s_waitcnt vmcnt(0)" ::: "memory");
      }
      __builtin_amdgcn_sched_barrier(0);
      __builtin_amdgcn_s_barrier();
      asm volatile("" ::: "memory");
    }
    cur = cur + 1; if (cur >= 3) cur -= 3;
  }

  // epilogue
#pragma unroll
  for (int mf = 0; mf < 4; ++mf) {
#pragma unroll
    for (int n = 0; n < 4; ++n) {
#pragma unroll
      for (int r = 0; r < 4; ++r) {
        int row = rowBase + wm * 64 + mf * 16 + g * 4 + r;
        int col = colBase + wn * 64 + n * 16 + c0;
        float v = acc[mf][n][r] + bias[col];
        if constexpr (MODE == MODE_QK) {
          int b = row >> 11, sI = row & 2047, hh = col >> 6, d = col & 63;
          ((unsigned short*)out)[(((size_t)(b * 16 + hh)) * 2048 + sI) * 64 + d] = f2bf(v);
        } else if constexpr (MODE == MODE_VT) {
          int b = row >> 11, sI = row & 2047, hh = col >> 6, d = col & 63;
          ((unsigned short*)out)[(((size_t)(b * 16 + hh)) * 64 + d) * 2048 + sI] = f2bf(v);
        } else if constexpr (MODE == MODE_RES) {
          ((float*)out)[(size_t)row * N + col] = resid[(size_t)row * N + col] + v;
        } else { // MODE_FFN1
          ((unsigned short*)out)[(size_t)row * N + col] = f2bf(fmaxf(v, 0.0f));
        }
      }
    }
  }
}

// ------------------------------------------------------------------
// Flash attention, swapped-operand form; exp2-domain softmax + cvt_pk pack.
// ------------------------------------------------------------------
__global__ __launch_bounds__(256) void attn_kernel(
    const unsigned short* __restrict__ q, const unsigned short* __restrict__ k,
    const unsigned short* __restrict__ vT, const int* __restrict__ mask,
    unsigned short* __restrict__ ctx)
{
  const int S = 2048, DK = 64, KVB = 64;
  const float SL2E = 0.125f * 1.44269504088896f;
  int bh = blockIdx.x;
  int b = bh >> 4, hh = bh & 15;
  int qbase = blockIdx.y * 64;
  int tid = threadIdx.x, lane = tid & 63, wid = tid >> 6;
  int g = lane >> 4, c0 = lane & 15;

  __shared__ unsigned short Ks[KVB][DK];
  __shared__ unsigned short Vs[DK][KVB];
  __shared__ float Msf[KVB];

  const unsigned short* qb = q  + (size_t)bh * S * DK;
  const unsigned short* kb = k  + (size_t)bh * S * DK;
  const unsigned short* vb = vT + (size_t)bh * DK * S;

  int qrow = qbase + wid * 16 + c0;
  v8s aq[2];
#pragma unroll
  for (int t = 0; t < 2; ++t)
    aq[t] = *reinterpret_cast<const v8s*>(&qb[(size_t)qrow * DK + t * 32 + g * 8]);

  f32x4 acc[4];
#pragma unroll
  for (int no = 0; no < 4; ++no) acc[no] = (f32x4){0.f, 0.f, 0.f, 0.f};
  float mrow = -1e30f, lrow = 0.f;

  for (int kt = 0; kt < S; kt += KVB) {
#pragma unroll
    for (int p = 0; p < 2; ++p) {
      int idx = tid + p * 256;
      int r = idx >> 3;
      int cb = (idx & 7) * 16;
      int sw = cb ^ ((r & 7) << 4);
      *reinterpret_cast<v8u*>((char*)&Ks[r][0] + sw) =
          *reinterpret_cast<const v8u*>((const char*)&kb[(size_t)(kt + r) * DK] + cb);
      *reinterpret_cast<v8u*>((char*)&Vs[r][0] + sw) =
          *reinterpret_cast<const v8u*>((const char*)&vb[(size_t)r * S + kt] + cb);
    }
    if (tid < KVB) Msf[tid] = mask[b * S + kt + tid] ? 0.f : -1e9f;
    __syncthreads();

    float p[16];
#pragma unroll
    for (int n = 0; n < 4; ++n) {
      f32x4 sa = (f32x4){0.f, 0.f, 0.f, 0.f};
#pragma unroll
      for (int t = 0; t < 2; ++t) {
        int kvr = n * 16 + c0;
        int cb = (t * 32 + g * 8) * 2;
        int sw = cb ^ ((kvr & 7) << 4);
        v8s ak = *reinterpret_cast<const v8s*>((const char*)&Ks[kvr][0] + sw);
        sa = __builtin_amdgcn_mfma_f32_16x16x32_bf16(ak, aq[t], sa, 0, 0, 0);
      }
      f32x4 bn = *reinterpret_cast<const f32x4*>(&Msf[n * 16 + g * 4]);
#pragma unroll
      for (int r = 0; r < 4; ++r) p[n * 4 + r] = sa[r] * SL2E + bn[r];
    }

    float tm = p[0];
#pragma unroll
    for (int i = 1; i < 16; ++i) tm = fmaxf(tm, p[i]);
    tm = fmaxf(tm, __shfl_xor(tm, 16));
    tm = fmaxf(tm, __shfl_xor(tm, 32));
    float mn = fmaxf(mrow, tm);
    float sc = exp2f(mrow - mn);
    float ts = 0.f;
#pragma unroll
    for (int i = 0; i < 16; ++i) { p[i] = exp2f(p[i] - mn); ts += p[i]; }
    ts += __shfl_xor(ts, 16);
    ts += __shfl_xor(ts, 32);
    lrow = lrow * sc + ts;
    mrow = mn;
#pragma unroll
    for (int no = 0; no < 4; ++no) {
      acc[no][0] *= sc; acc[no][1] *= sc; acc[no][2] *= sc; acc[no][3] *= sc;
    }

#pragma unroll
    for (int c = 0; c < 2; ++c) {
      union { v8s s; unsigned u[4]; } pk;
#pragma unroll
      for (int hph = 0; hph < 4; ++hph)
        asm("v_cvt_pk_bf16_f32 %0, %1, %2"
            : "=v"(pk.u[hph]) : "v"(p[c * 8 + 2 * hph]), "v"(p[c * 8 + 2 * hph + 1]));
      v8s pbv = pk.s;
#pragma unroll
      for (int no = 0; no < 4; ++no) {
        int d = no * 16 + c0;
        int sw = (d & 7) << 4;
        const char* vrow = (const char*)&Vs[d][0];
        v4s lo = *reinterpret_cast<const v4s*>(vrow + (((c * 64) + g * 8) ^ sw));
        v4s hi = *reinterpret_cast<const v4s*>(vrow + (((c * 64 + 32) + g * 8) ^ sw));
        v8s av = {lo[0], lo[1], lo[2], lo[3], hi[0], hi[1], hi[2], hi[3]};
        acc[no] = __builtin_amdgcn_mfma_f32_16x16x32_bf16(av, pbv, acc[no], 0, 0, 0);
      }
    }
    __syncthreads();
  }

  float inv = 1.0f / fmaxf(lrow, 1e-20f);
#pragma unroll
  for (int no = 0; no < 4; ++no) {
    v4u o;
    o[0] = f2bf(acc[no][0] * inv);
    o[1] = f2bf(acc[no][1] * inv);
    o[2] = f2bf(acc[no][2] * inv);
    o[3] = f2bf(acc[no][3] * inv);
    *reinterpret_cast<v4u*>(
        &ctx[(size_t)(b * S + qrow) * 1024 + hh * 64 + no * 16 + g * 4]) = o;
  }
}

// ------------------------------------------------------------------
extern "C" void kernel_launch(void* const* d_in, const int* in_sizes, int n_in,
                              void* d_out, int out_size, void* d_ws, size_t ws_size,
                              hipStream_t stream)
{
  (void)in_sizes; (void)n_in; (void)out_size; (void)ws_size;
  const float* x    = (const float*)d_in[0];
  const int*   mask = (const int*)d_in[1];
  const float* Wq = (const float*)d_in[2];  const float* bq = (const float*)d_in[3];
  const float* Wk = (const float*)d_in[4];  const float* bk = (const float*)d_in[5];
  const float* Wv = (const float*)d_in[6];  const float* bv = (const float*)d_in[7];
  const float* Wo = (const float*)d_in[8];  const float* bo = (const float*)d_in[9];
  const float* W1 = (const float*)d_in[10]; const float* b1 = (const float*)d_in[11];
  const float* W2 = (const float*)d_in[12]; const float* b2 = (const float*)d_in[13];
  const float* ln1a = (const float*)d_in[14]; const float* ln1b = (const float*)d_in[15];
  const float* ln2a = (const float*)d_in[16]; const float* ln2b = (const float*)d_in[17];

  char* ws = (char*)d_ws;
  const size_t MB = (size_t)1 << 20;
  unsigned short* wqT = (unsigned short*)(ws + 0 * MB);
  unsigned short* wkT = (unsigned short*)(ws + 2 * MB);
  unsigned short* wvT = (unsigned short*)(ws + 4 * MB);
  unsigned short* woT = (unsigned short*)(ws + 6 * MB);
  unsigned short* w1T = (unsigned short*)(ws + 8 * MB);   // [4096][1024]
  unsigned short* w2T = (unsigned short*)(ws + 16 * MB);  // [1024][4096]
  unsigned short* hb  = (unsigned short*)(ws + 24 * MB);  // LN out, 8192x1024
  unsigned short* qb  = (unsigned short*)(ws + 40 * MB);  // [bh][S][64]
  unsigned short* kb  = (unsigned short*)(ws + 56 * MB);
  unsigned short* vTb = (unsigned short*)(ws + 72 * MB);  // [bh][64][S]
  unsigned short* ctx = (unsigned short*)(ws + 88 * MB);  // 8192x1024
  unsigned short* gb  = (unsigned short*)(ws + 40 * MB);  // FFN mid (aliases q/k/v/ctx, dead)
  float* xout = (float*)d_out;

  dim3 tb(32, 8);
  transpose_convert<<<dim3(32, 32),  tb, 0, stream>>>(Wq, wqT, 1024, 1024);
  transpose_convert<<<dim3(32, 32),  tb, 0, stream>>>(Wk, wkT, 1024, 1024);
  transpose_convert<<<dim3(32, 32),  tb, 0, stream>>>(Wv, wvT, 1024, 1024);
  transpose_convert<<<dim3(32, 32),  tb, 0, stream>>>(Wo, woT, 1024, 1024);
  transpose_convert<<<dim3(128, 32), tb, 0, stream>>>(W1, w1T, 1024, 4096);
  transpose_convert<<<dim3(32, 128), tb, 0, stream>>>(W2, w2T, 4096, 1024);

  ln_kernel<<<8192, 256, 0, stream>>>(x, hb, ln1a, ln1b);

  // grids: (M/128)*(N/256) workgroups, 512 threads
  gemm_pipe<MODE_QK><<<256, 512, 0, stream>>>(hb, wqT, bq, nullptr, qb,  8192, 1024, 1024);
  gemm_pipe<MODE_QK><<<256, 512, 0, stream>>>(hb, wkT, bk, nullptr, kb,  8192, 1024, 1024);
  gemm_pipe<MODE_VT><<<256, 512, 0, stream>>>(hb, wvT, bv, nullptr, vTb, 8192, 1024, 1024);

  attn_kernel<<<dim3(64, 32), 256, 0, stream>>>(qb, kb, vTb, mask, ctx);

  gemm_pipe<MODE_RES><<<256, 512, 0, stream>>>(ctx, woT, bo, x, xout, 8192, 1024, 1024);

  ln_kernel<<<8192, 256, 0, stream>>>(xout, hb, ln2a, ln2b);

  gemm_pipe<MODE_FFN1><<<1024, 512, 0, stream>>>(hb, w1T, b1, nullptr, gb, 8192, 4096, 1024);
  gemm_pipe<MODE_RES><<<256, 512, 0, stream>>>(gb, w2T, b2, xout, xout, 8192, 1024, 4096);
}

// Round 5
// 448.687 us; speedup vs baseline: 1.7290x; 1.0810x over previous
//
#include <hip/hip_runtime.h>

typedef __attribute__((ext_vector_type(8))) short v8s;
typedef __attribute__((ext_vector_type(4))) short v4s;
typedef __attribute__((ext_vector_type(8))) unsigned short v8u;
typedef __attribute__((ext_vector_type(4))) unsigned short v4u;
typedef __attribute__((ext_vector_type(4))) float f32x4;

#define DEV __device__ __forceinline__

DEV unsigned short f2bf(float f) {
  union { float f; unsigned u; } v; v.f = f;
  unsigned r = v.u + 0x7fffu + ((v.u >> 16) & 1u);
  return (unsigned short)(r >> 16);
}

DEV void gload16(const unsigned short* g, unsigned short* l) {
  __builtin_amdgcn_global_load_lds(
      (const __attribute__((address_space(1))) unsigned int*)g,
      (__attribute__((address_space(3))) unsigned int*)l, 16, 0, 0);
}

// ------------------------------------------------------------------
// LayerNorm (torch-style: mean, std ddof=1, (x-mean)/(std+eps)) -> bf16
// ------------------------------------------------------------------
__global__ __launch_bounds__(256) void ln_kernel(
    const float* __restrict__ x, unsigned short* __restrict__ h,
    const float* __restrict__ alpha, const float* __restrict__ beta)
{
  int row = blockIdx.x;
  int tid = threadIdx.x;
  const float4* xr = reinterpret_cast<const float4*>(x + (size_t)row * 1024);
  float4 v = xr[tid];
  float s  = v.x + v.y + v.z + v.w;
  float ss = v.x * v.x + v.y * v.y + v.z * v.z + v.w * v.w;
#pragma unroll
  for (int off = 1; off < 64; off <<= 1) {
    s  += __shfl_xor(s, off);
    ss += __shfl_xor(ss, off);
  }
  __shared__ float ps[4][2];
  int wid = tid >> 6, lane = tid & 63;
  if (lane == 0) { ps[wid][0] = s; ps[wid][1] = ss; }
  __syncthreads();
  s  = ps[0][0] + ps[1][0] + ps[2][0] + ps[3][0];
  ss = ps[0][1] + ps[1][1] + ps[2][1] + ps[3][1];
  float mean = s * (1.0f / 1024.0f);
  float var  = (ss - 1024.0f * mean * mean) * (1.0f / 1023.0f);
  float inv  = 1.0f / (sqrtf(fmaxf(var, 0.0f)) + 1e-6f);
  float a = alpha[0], b = beta[0];
  v4u o;
  o[0] = f2bf(a * ((v.x - mean) * inv) + b);
  o[1] = f2bf(a * ((v.y - mean) * inv) + b);
  o[2] = f2bf(a * ((v.z - mean) * inv) + b);
  o[3] = f2bf(a * ((v.w - mean) * inv) + b);
  *reinterpret_cast<v4u*>(h + (size_t)row * 1024 + tid * 4) = o;
}

// ------------------------------------------------------------------
// fp32 W[K][N] -> bf16 Wt[N][K]
// ------------------------------------------------------------------
__global__ __launch_bounds__(256) void transpose_convert(
    const float* __restrict__ W, unsigned short* __restrict__ Wt, int K, int N)
{
  __shared__ float t[32][33];
  int n0 = blockIdx.x * 32, k0 = blockIdx.y * 32;
  int tx = threadIdx.x, ty = threadIdx.y;
#pragma unroll
  for (int i = 0; i < 4; ++i)
    t[ty + i * 8][tx] = W[(size_t)(k0 + ty + i * 8) * N + n0 + tx];
  __syncthreads();
#pragma unroll
  for (int i = 0; i < 4; ++i)
    Wt[(size_t)(n0 + ty + i * 8) * K + k0 + tx] = f2bf(t[tx][ty + i * 8]);
}

// ------------------------------------------------------------------
// Pipelined bf16 GEMM: tile 128x256, BK=64, 8 waves (2M x 4N),
// 3 LDS K-tile buffers, counted vmcnt(6), K-split phases
// (each fragment read once per K-tile), XOR-swizzled LDS via
// pre-swizzled global_load_lds source, setprio, bijective XCD swizzle.
// ------------------------------------------------------------------
enum { MODE_QK = 0, MODE_VT = 1, MODE_RES = 2, MODE_FFN1 = 3 };

#define BUF_ELEMS ((128 + 256) * 64)

DEV void stage_part(const unsigned short* Aptr, const unsigned short* Bptr,
                    unsigned short* buf, int K, int part, int wid, int lane)
{
  // part 0: A slab 0, B slabs 0,1 ; part 1: A slab 1, B slabs 2,3
  {
    int d = (part * 8 + wid) * 64 + lane;      // A granule 0..1023
    int r = d >> 3, p = d & 7;
    gload16(Aptr + (size_t)r * K + 8 * (p ^ (r & 7)),
            buf + (size_t)(part * 8 + wid) * 512);
  }
#pragma unroll
  for (int j = 0; j < 2; ++j) {
    int ib = part * 2 + j;
    int d = (ib * 8 + wid) * 64 + lane;        // B granule 0..2047
    int r = d >> 3, p = d & 7;
    gload16(Bptr + (size_t)r * K + 8 * (p ^ (r & 7)),
            buf + 128 * 64 + (size_t)(ib * 8 + wid) * 512);
  }
}

template <int MODE>
__global__ __launch_bounds__(512, 2) void gemm_pipe(
    const unsigned short* __restrict__ A, const unsigned short* __restrict__ Bt,
    const float* __restrict__ bias, const float* __restrict__ resid,
    void* __restrict__ out, int M, int N, int K)
{
  __shared__ unsigned short lds[3 * BUF_ELEMS];

  int nbx = M >> 7, nwg = gridDim.x;
  int lin = blockIdx.x;
  int qq = nwg >> 3, rr = nwg & 7;
  int xcd = lin & 7, idx = lin >> 3;
  int swz = (xcd < rr ? xcd * (qq + 1) : rr * (qq + 1) + (xcd - rr) * qq) + idx;
  int bx = swz % nbx, by = swz / nbx;

  int tid = threadIdx.x, lane = tid & 63, wid = tid >> 6;
  int wm = wid >> 2, wn = wid & 3;
  int g = lane >> 4, c0 = lane & 15;
  int rowBase = bx * 128, colBase = by * 256;

  const unsigned short* Ab = A  + (size_t)rowBase * K;
  const unsigned short* Bb = Bt + (size_t)colBase * K;
  int NT = K >> 6;

  f32x4 acc[4][4];
#pragma unroll
  for (int m = 0; m < 4; ++m)
#pragma unroll
    for (int n = 0; n < 4; ++n) acc[m][n] = (f32x4){0.f, 0.f, 0.f, 0.f};

  // prologue: stage tiles 0 and 1
  stage_part(Ab, Bb, lds, K, 0, wid, lane);
  stage_part(Ab, Bb, lds, K, 1, wid, lane);
  stage_part(Ab + 64, Bb + 64, lds + BUF_ELEMS, K, 0, wid, lane);
  stage_part(Ab + 64, Bb + 64, lds + BUF_ELEMS, K, 1, wid, lane);
  asm volatile("s_waitcnt vmcnt(6)" ::: "memory");
  __builtin_amdgcn_s_barrier();
  asm volatile("" ::: "memory");

  int cur = 0;
  for (int t = 0; t < NT; ++t) {
    const char* Abuf = (const char*)(lds + cur * BUF_ELEMS);
    const char* Bbuf = Abuf + 128 * 128;
    int nxt2 = cur + 2; if (nxt2 >= 3) nxt2 -= 3;
    unsigned short* sbuf = lds + nxt2 * BUF_ELEMS;
    bool doStage = (t + 2 < NT);
    int ks = (t + 2) << 6;
    int e = (c0 & 7) << 4;

#pragma unroll
    for (int ph = 0; ph < 2; ++ph) {           // ph = K-half: frags read ONCE
      v8s af[4], bfr[4];
#pragma unroll
      for (int m = 0; m < 4; ++m)
        af[m] = *reinterpret_cast<const v8s*>(
            Abuf + (wm * 64 + m * 16 + c0) * 128 + ((ph * 64 + g * 16) ^ e));
#pragma unroll
      for (int n = 0; n < 4; ++n)
        bfr[n] = *reinterpret_cast<const v8s*>(
            Bbuf + (wn * 64 + n * 16 + c0) * 128 + ((ph * 64 + g * 16) ^ e));

      if (doStage) stage_part(Ab + ks, Bb + ks, sbuf, K, ph, wid, lane);

      __builtin_amdgcn_s_setprio(1);
#pragma unroll
      for (int m = 0; m < 4; ++m)
#pragma unroll
        for (int n = 0; n < 4; ++n)
          acc[m][n] = __builtin_amdgcn_mfma_f32_16x16x32_bf16(
              af[m], bfr[n], acc[m][n], 0, 0, 0);
      __builtin_amdgcn_s_setprio(0);

      if (ph == 1) {
        if (doStage) asm volatile("s_waitcnt vmcnt(6)" ::: "memory");
        else         asm volatile("s_waitcnt vmcnt(0)" ::: "memory");
      }
      __builtin_amdgcn_sched_barrier(0);
      __builtin_amdgcn_s_barrier();
      asm volatile("" ::: "memory");
    }
    cur = cur + 1; if (cur >= 3) cur -= 3;
  }

  // epilogue
#pragma unroll
  for (int mf = 0; mf < 4; ++mf) {
#pragma unroll
    for (int n = 0; n < 4; ++n) {
#pragma unroll
      for (int r = 0; r < 4; ++r) {
        int row = rowBase + wm * 64 + mf * 16 + g * 4 + r;
        int col = colBase + wn * 64 + n * 16 + c0;
        float v = acc[mf][n][r] + bias[col];
        if constexpr (MODE == MODE_QK) {
          int b = row >> 11, sI = row & 2047, hh = col >> 6, d = col & 63;
          ((unsigned short*)out)[(((size_t)(b * 16 + hh)) * 2048 + sI) * 64 + d] = f2bf(v);
        } else if constexpr (MODE == MODE_VT) {
          int b = row >> 11, sI = row & 2047, hh = col >> 6, d = col & 63;
          ((unsigned short*)out)[(((size_t)(b * 16 + hh)) * 64 + d) * 2048 + sI] = f2bf(v);
        } else if constexpr (MODE == MODE_RES) {
          ((float*)out)[(size_t)row * N + col] = resid[(size_t)row * N + col] + v;
        } else { // MODE_FFN1
          ((unsigned short*)out)[(size_t)row * N + col] = f2bf(fmaxf(v, 0.0f));
        }
      }
    }
  }
}

// ------------------------------------------------------------------
// Flash attention v3: swapped QK^T, double-buffered LDS, async-STAGE,
// K via global_load_lds (pre-swizzled source), V in k-slot-permuted
// LDS layout (single b128 PV operand reads), defer-max softmax.
// ------------------------------------------------------------------
DEV void writeV(unsigned short* Vbuf, int idx, v8u vv) {
  int d = idx >> 3, k0 = (idx & 7) * 8;
  // slot(k) = 32*(k>>5) + 8*((k>>2)&3) + 4*((k>>4)&1) + (k&3)
  int slot0 = ((k0 >> 5) << 5) + (((k0 >> 2) & 3) << 3) + (((k0 >> 4) & 1) << 2);
  int b0 = (slot0 * 2) ^ ((d & 7) << 4);
  char* base = (char*)(Vbuf + d * 64);
  v4u lo = {vv[0], vv[1], vv[2], vv[3]};
  v4u hi = {vv[4], vv[5], vv[6], vv[7]};
  *reinterpret_cast<v4u*>(base + b0) = lo;
  *reinterpret_cast<v4u*>(base + (b0 ^ 16)) = hi;
}

__global__ __launch_bounds__(256) void attn_kernel(
    const unsigned short* __restrict__ q, const unsigned short* __restrict__ k,
    const unsigned short* __restrict__ vT, const int* __restrict__ mask,
    unsigned short* __restrict__ ctx)
{
  const int S = 2048, DK = 64, KVB = 64, NT = 32;
  const float SL2E = 0.125f * 1.44269504088896f;
  int bh = blockIdx.x;
  int b = bh >> 4, hh = bh & 15;
  int qbase = blockIdx.y * 64;
  int tid = threadIdx.x, lane = tid & 63, wid = tid >> 6;
  int g = lane >> 4, c0 = lane & 15;

  __shared__ unsigned short Ks[2][KVB * DK];  // [kv][dk], content col-swizzled
  __shared__ unsigned short Vs[2][DK * KVB];  // [d][slot], permuted + swizzled
  __shared__ float Msf[2][KVB];

  const unsigned short* qb = q  + (size_t)bh * S * DK;
  const unsigned short* kb = k  + (size_t)bh * S * DK;
  const unsigned short* vb = vT + (size_t)bh * DK * S;
  const int* mb = mask + b * S;

  int qrow = qbase + wid * 16 + c0;
  v8s aq[2];
#pragma unroll
  for (int t = 0; t < 2; ++t)
    aq[t] = *reinterpret_cast<const v8s*>(&qb[(size_t)qrow * DK + t * 32 + g * 8]);

  // staging indices (per thread, 2 granules)
  int i0 = tid, i1 = tid + 256;
  int r0 = i0 >> 3, m0 = i0 & 7;
  int r1 = i1 >> 3, m1 = i1 & 7;

  f32x4 acc[4];
#pragma unroll
  for (int no = 0; no < 4; ++no) acc[no] = (f32x4){0.f, 0.f, 0.f, 0.f};
  float mrow = -1e30f, lrow = 0.f;

  // ---- prologue: stage tile 0 ----
  {
    gload16(kb + (size_t)r0 * DK + 8 * (m0 ^ (r0 & 7)), &Ks[0][i0 * 8]);
    gload16(kb + (size_t)r1 * DK + 8 * (m1 ^ (r1 & 7)), &Ks[0][i1 * 8]);
    v8u vv0 = *reinterpret_cast<const v8u*>(&vb[(size_t)r0 * S + m0 * 8]);
    v8u vv1 = *reinterpret_cast<const v8u*>(&vb[(size_t)r1 * S + m1 * 8]);
    writeV(Vs[0], i0, vv0);
    writeV(Vs[0], i1, vv1);
    if (tid < KVB) Msf[0][tid] = mb[tid] ? 0.f : -1e9f;
    __syncthreads();
  }

  for (int t = 0; t < NT; ++t) {
    int cur = t & 1, nxt = cur ^ 1;
    int ktn = (t + 1) * KVB;
    bool more = (t + 1 < NT);
    v8u vv0, vv1; float msv = 0.f;
    if (more) {
      gload16(kb + (size_t)(ktn + r0) * DK + 8 * (m0 ^ (r0 & 7)), &Ks[nxt][i0 * 8]);
      gload16(kb + (size_t)(ktn + r1) * DK + 8 * (m1 ^ (r1 & 7)), &Ks[nxt][i1 * 8]);
      vv0 = *reinterpret_cast<const v8u*>(&vb[(size_t)r0 * S + ktn + m0 * 8]);
      vv1 = *reinterpret_cast<const v8u*>(&vb[(size_t)r1 * S + ktn + m1 * 8]);
      if (tid < KVB) msv = mb[ktn + tid] ? 0.f : -1e9f;
    }

    // ---- QK^T (swapped): p[n*4+r] = S^T[k=n*16+g*4+r][q=c0] ----
    float p[16];
#pragma unroll
    for (int n = 0; n < 4; ++n) {
      f32x4 sa = (f32x4){0.f, 0.f, 0.f, 0.f};
      int kvr = n * 16 + c0;
      const char* krow = (const char*)&Ks[cur][kvr * DK];
      int sw = (kvr & 7) << 4;
#pragma unroll
      for (int tt = 0; tt < 2; ++tt) {
        v8s ak = *reinterpret_cast<const v8s*>(krow + ((tt * 64 + g * 16) ^ sw));
        sa = __builtin_amdgcn_mfma_f32_16x16x32_bf16(ak, aq[tt], sa, 0, 0, 0);
      }
      f32x4 bn = *reinterpret_cast<const f32x4*>(&Msf[cur][n * 16 + g * 4]);
#pragma unroll
      for (int r = 0; r < 4; ++r) p[n * 4 + r] = sa[r] * SL2E + bn[r];
    }

    // ---- online softmax (defer-max, THR=8 in log2 domain) ----
    float pmax = p[0];
#pragma unroll
    for (int i = 1; i < 16; ++i) pmax = fmaxf(pmax, p[i]);
    pmax = fmaxf(pmax, __shfl_xor(pmax, 16));
    pmax = fmaxf(pmax, __shfl_xor(pmax, 32));
    if (!__all(pmax - mrow <= 8.0f)) {
      float mn = fmaxf(mrow, pmax);
      float sc = exp2f(mrow - mn);
      lrow *= sc;
#pragma unroll
      for (int no = 0; no < 4; ++no) {
        acc[no][0] *= sc; acc[no][1] *= sc; acc[no][2] *= sc; acc[no][3] *= sc;
      }
      mrow = mn;
    }
    float ts = 0.f;
#pragma unroll
    for (int i = 0; i < 16; ++i) { p[i] = exp2f(p[i] - mrow); ts += p[i]; }
    ts += __shfl_xor(ts, 16);
    ts += __shfl_xor(ts, 32);
    lrow += ts;

    // ---- pack P to bf16 ----
    v8s pbv[2];
#pragma unroll
    for (int c = 0; c < 2; ++c) {
      union { v8s s; unsigned u[4]; } pk;
#pragma unroll
      for (int hph = 0; hph < 4; ++hph)
        asm("v_cvt_pk_bf16_f32 %0, %1, %2"
            : "=v"(pk.u[hph]) : "v"(p[c * 8 + 2 * hph]), "v"(p[c * 8 + 2 * hph + 1]));
      pbv[c] = pk.s;
    }

    // ---- PV: single b128 operand reads from permuted V ----
#pragma unroll
    for (int c = 0; c < 2; ++c) {
#pragma unroll
      for (int no = 0; no < 4; ++no) {
        int d = no * 16 + c0;
        v8s av = *reinterpret_cast<const v8s*>(
            (const char*)&Vs[cur][d * 64] + ((c * 64 + g * 16) ^ ((d & 7) << 4)));
        acc[no] = __builtin_amdgcn_mfma_f32_16x16x32_bf16(av, pbv[c], acc[no], 0, 0, 0);
      }
    }

    // ---- publish next tile ----
    if (more) {
      writeV(Vs[nxt], i0, vv0);
      writeV(Vs[nxt], i1, vv1);
      if (tid < KVB) Msf[nxt][tid] = msv;
    }
    __syncthreads();
  }

  float inv = 1.0f / fmaxf(lrow, 1e-20f);
#pragma unroll
  for (int no = 0; no < 4; ++no) {
    v4u o;
    o[0] = f2bf(acc[no][0] * inv);
    o[1] = f2bf(acc[no][1] * inv);
    o[2] = f2bf(acc[no][2] * inv);
    o[3] = f2bf(acc[no][3] * inv);
    *reinterpret_cast<v4u*>(
        &ctx[(size_t)(b * S + qrow) * 1024 + hh * 64 + no * 16 + g * 4]) = o;
  }
}

// ------------------------------------------------------------------
extern "C" void kernel_launch(void* const* d_in, const int* in_sizes, int n_in,
                              void* d_out, int out_size, void* d_ws, size_t ws_size,
                              hipStream_t stream)
{
  (void)in_sizes; (void)n_in; (void)out_size; (void)ws_size;
  const float* x    = (const float*)d_in[0];
  const int*   mask = (const int*)d_in[1];
  const float* Wq = (const float*)d_in[2];  const float* bq = (const float*)d_in[3];
  const float* Wk = (const float*)d_in[4];  const float* bk = (const float*)d_in[5];
  const float* Wv = (const float*)d_in[6];  const float* bv = (const float*)d_in[7];
  const float* Wo = (const float*)d_in[8];  const float* bo = (const float*)d_in[9];
  const float* W1 = (const float*)d_in[10]; const float* b1 = (const float*)d_in[11];
  const float* W2 = (const float*)d_in[12]; const float* b2 = (const float*)d_in[13];
  const float* ln1a = (const float*)d_in[14]; const float* ln1b = (const float*)d_in[15];
  const float* ln2a = (const float*)d_in[16]; const float* ln2b = (const float*)d_in[17];

  char* ws = (char*)d_ws;
  const size_t MB = (size_t)1 << 20;
  unsigned short* wqT = (unsigned short*)(ws + 0 * MB);
  unsigned short* wkT = (unsigned short*)(ws + 2 * MB);
  unsigned short* wvT = (unsigned short*)(ws + 4 * MB);
  unsigned short* woT = (unsigned short*)(ws + 6 * MB);
  unsigned short* w1T = (unsigned short*)(ws + 8 * MB);   // [4096][1024]
  unsigned short* w2T = (unsigned short*)(ws + 16 * MB);  // [1024][4096]
  unsigned short* hb  = (unsigned short*)(ws + 24 * MB);  // LN out, 8192x1024
  unsigned short* qb  = (unsigned short*)(ws + 40 * MB);  // [bh][S][64]
  unsigned short* kb  = (unsigned short*)(ws + 56 * MB);
  unsigned short* vTb = (unsigned short*)(ws + 72 * MB);  // [bh][64][S]
  unsigned short* ctx = (unsigned short*)(ws + 88 * MB);  // 8192x1024
  unsigned short* gb  = (unsigned short*)(ws + 40 * MB);  // FFN mid (aliases q/k/v/ctx, dead)
  float* xout = (float*)d_out;

  dim3 tb(32, 8);
  transpose_convert<<<dim3(32, 32),  tb, 0, stream>>>(Wq, wqT, 1024, 1024);
  transpose_convert<<<dim3(32, 32),  tb, 0, stream>>>(Wk, wkT, 1024, 1024);
  transpose_convert<<<dim3(32, 32),  tb, 0, stream>>>(Wv, wvT, 1024, 1024);
  transpose_convert<<<dim3(32, 32),  tb, 0, stream>>>(Wo, woT, 1024, 1024);
  transpose_convert<<<dim3(128, 32), tb, 0, stream>>>(W1, w1T, 1024, 4096);
  transpose_convert<<<dim3(32, 128), tb, 0, stream>>>(W2, w2T, 4096, 1024);

  ln_kernel<<<8192, 256, 0, stream>>>(x, hb, ln1a, ln1b);

  gemm_pipe<MODE_QK><<<256, 512, 0, stream>>>(hb, wqT, bq, nullptr, qb,  8192, 1024, 1024);
  gemm_pipe<MODE_QK><<<256, 512, 0, stream>>>(hb, wkT, bk, nullptr, kb,  8192, 1024, 1024);
  gemm_pipe<MODE_VT><<<256, 512, 0, stream>>>(hb, wvT, bv, nullptr, vTb, 8192, 1024, 1024);

  attn_kernel<<<dim3(64, 32), 256, 0, stream>>>(qb, kb, vTb, mask, ctx);

  gemm_pipe<MODE_RES><<<256, 512, 0, stream>>>(ctx, woT, bo, x, xout, 8192, 1024, 1024);

  ln_kernel<<<8192, 256, 0, stream>>>(xout, hb, ln2a, ln2b);

  gemm_pipe<MODE_FFN1><<<1024, 512, 0, stream>>>(hb, w1T, b1, nullptr, gb, 8192, 4096, 1024);
  gemm_pipe<MODE_RES><<<256, 512, 0, stream>>>(gb, w2T, b2, xout, xout, 8192, 1024, 4096);
}